// Round 1
// baseline (772.530 us; speedup 1.0000x reference)
//
#include <hip/hip_runtime.h>

#define NEG 0.2f

__device__ __forceinline__ float lrelu(float x) { return x >= 0.f ? x : NEG * x; }
__device__ __forceinline__ float elu1(float x) { return x > 0.f ? x : __expf(x) - 1.f; }

// ----------------- CSR build -----------------
__global__ void hist_kernel(const int* __restrict__ dst, int e, int* __restrict__ deg) {
    int i = blockIdx.x * blockDim.x + threadIdx.x;
    if (i < e) atomicAdd(&deg[dst[i]], 1);
}

__device__ __forceinline__ int waveIncScanI(int v, int lane) {
#pragma unroll
    for (int off = 1; off < 64; off <<= 1) {
        int u = __shfl_up(v, off);
        if (lane >= off) v += u;
    }
    return v;
}

__global__ void scan1_kernel(const int* __restrict__ deg, int n,
                             int* __restrict__ rowp, int* __restrict__ bsums) {
    int t = threadIdx.x;
    int base = blockIdx.x * 2048 + t * 8;
    int vals[8];
    int sum = 0;
#pragma unroll
    for (int i = 0; i < 8; ++i) {
        int idx = base + i;
        int v = (idx < n) ? deg[idx] : 0;
        vals[i] = sum;
        sum += v;
    }
    int lane = t & 63, w = t >> 6;
    int inc = waveIncScanI(sum, lane);
    __shared__ int wsums[4];
    if (lane == 63) wsums[w] = inc;
    __syncthreads();
    int wpre = 0;
#pragma unroll
    for (int i = 0; i < 3; ++i) wpre += (i < w) ? wsums[i] : 0;
    int exc = wpre + inc - sum;
#pragma unroll
    for (int i = 0; i < 8; ++i) {
        int idx = base + i;
        if (idx < n) rowp[idx] = exc + vals[i];
    }
    if (t == 255) bsums[blockIdx.x] = wpre + inc;
}

__global__ void scan2_kernel(int* bsums, int nb) {
    int lane = threadIdx.x & 63;
    int run = 0;
    for (int base = 0; base < nb; base += 64) {
        int i = base + lane;
        int v = (i < nb) ? bsums[i] : 0;
        int inc = waveIncScanI(v, lane);
        if (i < nb) bsums[i] = run + inc - v;
        run += __shfl(inc, 63);
    }
}

__global__ void scan3_kernel(int* __restrict__ rowp, const int* __restrict__ bsums,
                             int n, int total, int* __restrict__ cursor) {
    int i = blockIdx.x * blockDim.x + threadIdx.x;
    if (i < n) {
        int v = rowp[i] + bsums[i >> 11];
        rowp[i] = v;
        cursor[i] = v;
    } else if (i == n) {
        rowp[n] = total;
    }
}

__global__ void fill_kernel(const int* __restrict__ src, const int* __restrict__ dst, int e,
                            int* __restrict__ cursor, int* __restrict__ col) {
    int i = blockIdx.x * blockDim.x + threadIdx.x;
    if (i < e) {
        int pos = atomicAdd(&cursor[dst[i]], 1);
        col[pos] = src[i];
    }
}

// ----------------- fp32 GEMM  out[n,128] = A[n,128] @ W[128,128] (+bias) -----------------
__global__ __launch_bounds__(256, 2) void gemm128_kernel(
    const float* __restrict__ A, const float* __restrict__ W,
    const float* __restrict__ bias, float* __restrict__ out, int n) {
    __shared__ float ws_[128 * 128];
    __shared__ float xs[32 * 128];
    int t = threadIdx.x;
#pragma unroll
    for (int i = 0; i < 16; ++i)
        ((float4*)ws_)[i * 256 + t] = ((const float4*)W)[i * 256 + t];

    int rpb = (((n + (int)gridDim.x - 1) / (int)gridDim.x) + 31) & ~31;
    int rowStart = blockIdx.x * rpb;
    int rowEnd = min(n, rowStart + rpb);
    int rg = t >> 5, cg = t & 31;
    float4 bv = make_float4(0.f, 0.f, 0.f, 0.f);
    if (bias) bv = ((const float4*)bias)[cg];
    __syncthreads();

    for (int r0 = rowStart; r0 < rowEnd; r0 += 32) {
#pragma unroll
        for (int i = 0; i < 4; ++i) {
            int idx = i * 256 + t;
            int row = idx >> 5, col4 = idx & 31;
            int gr = r0 + row;
            float4 v = make_float4(0.f, 0.f, 0.f, 0.f);
            if (gr < n) v = ((const float4*)(A + (size_t)gr * 128))[col4];
            ((float4*)xs)[idx] = v;
        }
        __syncthreads();
        float acc[4][4];
#pragma unroll
        for (int i = 0; i < 4; ++i)
#pragma unroll
            for (int j = 0; j < 4; ++j) acc[i][j] = 0.f;

        const float* xb = xs + rg * 4 * 128;
        const float* wb = ws_ + cg * 4;
#pragma unroll 4
        for (int k4 = 0; k4 < 32; ++k4) {
            float4 xv[4], wv[4];
#pragma unroll
            for (int i = 0; i < 4; ++i) xv[i] = *(const float4*)(xb + i * 128 + k4 * 4);
#pragma unroll
            for (int kk = 0; kk < 4; ++kk) wv[kk] = *(const float4*)(wb + (k4 * 4 + kk) * 128);
#pragma unroll
            for (int i = 0; i < 4; ++i) {
                float x0 = xv[i].x, x1 = xv[i].y, x2 = xv[i].z, x3 = xv[i].w;
                acc[i][0] += x0 * wv[0].x + x1 * wv[1].x + x2 * wv[2].x + x3 * wv[3].x;
                acc[i][1] += x0 * wv[0].y + x1 * wv[1].y + x2 * wv[2].y + x3 * wv[3].y;
                acc[i][2] += x0 * wv[0].z + x1 * wv[1].z + x2 * wv[2].z + x3 * wv[3].z;
                acc[i][3] += x0 * wv[0].w + x1 * wv[1].w + x2 * wv[2].w + x3 * wv[3].w;
            }
        }
#pragma unroll
        for (int i = 0; i < 4; ++i) {
            int r = r0 + rg * 4 + i;
            if (r < n) {
                float4 o = make_float4(acc[i][0] + bv.x, acc[i][1] + bv.y,
                                       acc[i][2] + bv.z, acc[i][3] + bv.w);
                *(float4*)(out + (size_t)r * 128 + cg * 4) = o;
            }
        }
        __syncthreads();
    }
}

// ----------------- attention logits al_s/al_d [n,4] from hp [n,128] -----------------
__global__ void al_kernel(const float* __restrict__ hp, const float* __restrict__ asrc,
                          const float* __restrict__ adst, int n,
                          float* __restrict__ al_s, float* __restrict__ al_d) {
    int lane = threadIdx.x & 63;
    int q = lane & 3;   // head
    int ng = lane >> 2; // node-in-group 0..15
    float4 as4[8], ad4[8];
#pragma unroll
    for (int i = 0; i < 8; ++i) {
        as4[i] = ((const float4*)(asrc + q * 32))[i];
        ad4[i] = ((const float4*)(adst + q * 32))[i];
    }
    int wid = (blockIdx.x * blockDim.x + threadIdx.x) >> 6;
    int nwaves = (gridDim.x * blockDim.x) >> 6;
    for (int base = wid * 16; base < n; base += nwaves * 16) {
        int node = base + ng;
        if (node < n) {
            const float4* row = (const float4*)(hp + (size_t)node * 128 + q * 32);
            float s = 0.f, d = 0.f;
#pragma unroll
            for (int i = 0; i < 8; ++i) {
                float4 v = row[i];
                s += v.x * as4[i].x + v.y * as4[i].y + v.z * as4[i].z + v.w * as4[i].w;
                d += v.x * ad4[i].x + v.y * ad4[i].y + v.z * ad4[i].z + v.w * ad4[i].w;
            }
            al_s[node * 4 + q] = s;
            al_d[node * 4 + q] = d;
        }
    }
}

// ----------------- GAT aggregation: one wave per dst node -----------------
template <bool CONCAT>
__global__ void agg_kernel(const float* __restrict__ hp, const float* __restrict__ als,
                           const float* __restrict__ ald_, const int* __restrict__ rowp,
                           const int* __restrict__ col, const float* __restrict__ bias,
                           float* __restrict__ out, int n) {
    int wid = (blockIdx.x * blockDim.x + threadIdx.x) >> 6;
    if (wid >= n) return;
    int lane = threadIdx.x & 63;
    int d = wid;
    int h = lane >> 4;  // head of this lane's 2 channels
    int c2 = lane * 2;  // channel base 0..126
    float aldv = ald_[d * 4 + h];
    float zs = lrelu(als[d * 4 + h] + aldv); // self-loop logit
    float m = zs;
    int start = rowp[d], end = rowp[d + 1];
    for (int p = start; p < end; ++p) {
        int s = col[p];
        m = fmaxf(m, lrelu(als[s * 4 + h] + aldv));
    }
    float eself = __expf(zs - m);
    float2 v = *(const float2*)(hp + (size_t)d * 128 + c2);
    float a0 = eself * v.x, a1 = eself * v.y;
    float esum = eself;
    for (int p = start; p < end; ++p) {
        int s = col[p];
        float e = __expf(lrelu(als[s * 4 + h] + aldv) - m);
        float2 u = *(const float2*)(hp + (size_t)s * 128 + c2);
        a0 += e * u.x;
        a1 += e * u.y;
        esum += e;
    }
    float inv = 1.f / (esum + 1e-16f);
    a0 *= inv;
    a1 *= inv;
    if (CONCAT) {
        a0 = elu1(a0 + bias[c2]);
        a1 = elu1(a1 + bias[c2 + 1]);
        *(float2*)(out + (size_t)d * 128 + c2) = make_float2(a0, a1);
    } else {
        // mean over heads: combine lanes {l, l^16, l^32, l^48}
        a0 += __shfl_xor(a0, 16); a0 += __shfl_xor(a0, 32);
        a1 += __shfl_xor(a1, 16); a1 += __shfl_xor(a1, 32);
        if (lane < 16) {
            float r0 = elu1(a0 * 0.25f + bias[c2]);
            float r1 = elu1(a1 * 0.25f + bias[c2 + 1]);
            *(float2*)(out + (size_t)d * 32 + c2) = make_float2(r0, r1);
        }
    }
}

// ----------------- mean pool per batch segment (batch sorted) -----------------
__global__ void pool_kernel(const float* __restrict__ h2, const int* __restrict__ batch,
                            int n, float* __restrict__ pooled) {
    int b = blockIdx.x;
    __shared__ int sb[2];
    if (threadIdx.x == 0) {
        int lo = 0, hi = n;
        while (lo < hi) { int mid = (lo + hi) >> 1; if (batch[mid] < b) lo = mid + 1; else hi = mid; }
        sb[0] = lo;
        int lo2 = lo, hi2 = n;
        while (lo2 < hi2) { int mid = (lo2 + hi2) >> 1; if (batch[mid] < b + 1) lo2 = mid + 1; else hi2 = mid; }
        sb[1] = lo2;
    }
    __syncthreads();
    int lo = sb[0], hi = sb[1];
    int c = threadIdx.x & 31, g = threadIdx.x >> 5; // 8 groups of 32
    float acc = 0.f;
    for (int i = lo + g; i < hi; i += 8) acc += h2[(size_t)i * 32 + c];
    __shared__ float red[8][32];
    red[g][c] = acc;
    __syncthreads();
    if (threadIdx.x < 32) {
        float s = 0.f;
#pragma unroll
        for (int g2 = 0; g2 < 8; ++g2) s += red[g2][threadIdx.x];
        float cnt = (float)(hi - lo);
        pooled[b * 32 + threadIdx.x] = s / fmaxf(cnt, 1.f);
    }
}

// ----------------- final_proj + MLP head, one block per batch row -----------------
__global__ void mlp_kernel(const float* __restrict__ pooled, const float* __restrict__ w_fp,
                           const float* __restrict__ b_fp, const float* __restrict__ w_m1,
                           const float* __restrict__ b_m1, const float* __restrict__ w_m2,
                           const float* __restrict__ b_m2, float* __restrict__ out) {
    int b = blockIdx.x, t = threadIdx.x; // 128 threads
    __shared__ float sp[32], so[128];
    if (t < 32) sp[t] = pooled[b * 32 + t];
    __syncthreads();
    float o = b_fp[t];
#pragma unroll 8
    for (int k = 0; k < 32; ++k) o += sp[k] * w_fp[k * 128 + t];
    so[t] = o;
    __syncthreads();
    if (t < 64) {
        float hm = b_m1[t];
        for (int c = 0; c < 128; ++c) hm += so[c] * w_m1[c * 64 + t];
        float v = fmaxf(hm, 0.f) * w_m2[t];
#pragma unroll
        for (int offd = 32; offd > 0; offd >>= 1) v += __shfl_down(v, offd);
        if (t == 0) out[b] = v + b_m2[0];
    }
}

extern "C" void kernel_launch(void* const* d_in, const int* in_sizes, int n_in,
                              void* d_out, int out_size, void* d_ws, size_t ws_size,
                              hipStream_t stream) {
    const float* x = (const float*)d_in[0];
    const int* ei = (const int*)d_in[1];
    const int* batch = (const int*)d_in[2];
    const float* w_in = (const float*)d_in[3];
    const float* b_in = (const float*)d_in[4];
    const float* w[3] = {(const float*)d_in[5], (const float*)d_in[9], (const float*)d_in[13]};
    const float* asrc[3] = {(const float*)d_in[6], (const float*)d_in[10], (const float*)d_in[14]};
    const float* adst[3] = {(const float*)d_in[7], (const float*)d_in[11], (const float*)d_in[15]};
    const float* bb[3] = {(const float*)d_in[8], (const float*)d_in[12], (const float*)d_in[16]};
    const float* w_fp = (const float*)d_in[17];
    const float* b_fp = (const float*)d_in[18];
    const float* w_m1 = (const float*)d_in[19];
    const float* b_m1 = (const float*)d_in[20];
    const float* w_m2 = (const float*)d_in[21];
    const float* b_m2 = (const float*)d_in[22];

    int n = in_sizes[0] / 128;
    int e = in_sizes[1] / 2;
    int B = out_size;

    char* wsb = (char*)d_ws;
    size_t off = 0;
    auto alloc = [&](size_t bytes) -> void* {
        void* p = wsb + off;
        off += (bytes + 255) & ~(size_t)255;
        return p;
    };
    float* hA = (float*)alloc((size_t)n * 128 * 4);
    float* hB = (float*)alloc((size_t)n * 128 * 4);
    float* als = (float*)alloc((size_t)n * 4 * 4);
    float* ald = (float*)alloc((size_t)n * 4 * 4);
    int* deg = (int*)alloc((size_t)n * 4);       // reused as cursor
    int* rowp = (int*)alloc((size_t)(n + 1) * 4);
    int* col = (int*)alloc((size_t)e * 4);
    int* bsums = (int*)alloc(4096);
    float* pooled = (float*)alloc((size_t)B * 32 * 4);

    const int* srcp = ei;
    const int* dstp = ei + e;

    // CSR by dst (graph shared by all 3 layers)
    hipMemsetAsync(deg, 0, (size_t)n * 4, stream);
    hist_kernel<<<(e + 255) / 256, 256, 0, stream>>>(dstp, e, deg);
    int nb = (n + 2047) / 2048;
    scan1_kernel<<<nb, 256, 0, stream>>>(deg, n, rowp, bsums);
    scan2_kernel<<<1, 64, 0, stream>>>(bsums, nb);
    scan3_kernel<<<(n + 256) / 256, 256, 0, stream>>>(rowp, bsums, n, e, deg);
    fill_kernel<<<(e + 255) / 256, 256, 0, stream>>>(srcp, dstp, e, deg, col);

    // input projection
    gemm128_kernel<<<512, 256, 0, stream>>>(x, w_in, b_in, hA, n);

    // 3 GAT layers: gemm hA->hB, al from hB, aggregate hB->hA
    for (int L = 0; L < 3; ++L) {
        gemm128_kernel<<<512, 256, 0, stream>>>(hA, w[L], nullptr, hB, n);
        al_kernel<<<512, 256, 0, stream>>>(hB, asrc[L], adst[L], n, als, ald);
        int gridAgg = (n + 3) / 4;
        if (L < 2)
            agg_kernel<true><<<gridAgg, 256, 0, stream>>>(hB, als, ald, rowp, col, bb[L], hA, n);
        else
            agg_kernel<false><<<gridAgg, 256, 0, stream>>>(hB, als, ald, rowp, col, bb[L], hA, n);
    }

    // pooling over batch segments, then MLP head
    pool_kernel<<<B, 256, 0, stream>>>(hA, batch, n, pooled);
    mlp_kernel<<<B, 128, 0, stream>>>(pooled, w_fp, b_fp, w_m1, b_m1, w_m2, b_m2, (float*)d_out);
}

// Round 2
// 568.573 us; speedup vs baseline: 1.3587x; 1.3587x over previous
//
#include <hip/hip_runtime.h>

#define NEG 0.2f

__device__ __forceinline__ float lrelu(float x) { return x >= 0.f ? x : NEG * x; }
__device__ __forceinline__ float elu1(float x) { return x > 0.f ? x : __expf(x) - 1.f; }

// ----------------- CSR build -----------------
__global__ void hist_kernel(const int* __restrict__ dst, int e, int* __restrict__ deg) {
    int i = blockIdx.x * blockDim.x + threadIdx.x;
    if (i < e) atomicAdd(&deg[dst[i]], 1);
}

__device__ __forceinline__ int waveIncScanI(int v, int lane) {
#pragma unroll
    for (int off = 1; off < 64; off <<= 1) {
        int u = __shfl_up(v, off);
        if (lane >= off) v += u;
    }
    return v;
}

__global__ void scan1_kernel(const int* __restrict__ deg, int n,
                             int* __restrict__ rowp, int* __restrict__ bsums) {
    int t = threadIdx.x;
    int base = blockIdx.x * 2048 + t * 8;
    int vals[8];
    int sum = 0;
#pragma unroll
    for (int i = 0; i < 8; ++i) {
        int idx = base + i;
        int v = (idx < n) ? deg[idx] : 0;
        vals[i] = sum;
        sum += v;
    }
    int lane = t & 63, w = t >> 6;
    int inc = waveIncScanI(sum, lane);
    __shared__ int wsums[4];
    if (lane == 63) wsums[w] = inc;
    __syncthreads();
    int wpre = 0;
#pragma unroll
    for (int i = 0; i < 3; ++i) wpre += (i < w) ? wsums[i] : 0;
    int exc = wpre + inc - sum;
#pragma unroll
    for (int i = 0; i < 8; ++i) {
        int idx = base + i;
        if (idx < n) rowp[idx] = exc + vals[i];
    }
    if (t == 255) bsums[blockIdx.x] = wpre + inc;
}

__global__ void scan2_kernel(int* bsums, int nb) {
    int lane = threadIdx.x & 63;
    int run = 0;
    for (int base = 0; base < nb; base += 64) {
        int i = base + lane;
        int v = (i < nb) ? bsums[i] : 0;
        int inc = waveIncScanI(v, lane);
        if (i < nb) bsums[i] = run + inc - v;
        run += __shfl(inc, 63);
    }
}

__global__ void scan3_kernel(int* __restrict__ rowp, const int* __restrict__ bsums,
                             int n, int total, int* __restrict__ cursor) {
    int i = blockIdx.x * blockDim.x + threadIdx.x;
    if (i < n) {
        int v = rowp[i] + bsums[i >> 11];
        rowp[i] = v;
        cursor[i] = v;
    } else if (i == n) {
        rowp[n] = total;
    }
}

__global__ void fill_kernel(const int* __restrict__ src, const int* __restrict__ dst, int e,
                            int* __restrict__ cursor, int* __restrict__ col) {
    int i = blockIdx.x * blockDim.x + threadIdx.x;
    if (i < e) {
        int pos = atomicAdd(&cursor[dst[i]], 1);
        col[pos] = src[i];
    }
}

// ----------------- fp32 GEMM  out[n,128] = A[n,128] @ W[128,128] (+bias)
// FUSE_AL: also emit als[r,h] = dot(out[r, h*32:h*32+32], asrc[h]),  ald likewise.
template <bool FUSE_AL>
__global__ __launch_bounds__(256, 2) void gemm128_kernel(
    const float* __restrict__ A, const float* __restrict__ W,
    const float* __restrict__ bias, float* __restrict__ out, int n,
    const float* __restrict__ asrc, const float* __restrict__ adst,
    float* __restrict__ als, float* __restrict__ ald) {
    __shared__ float ws_[128 * 128];
    __shared__ float xs[32 * 128];
    int t = threadIdx.x;
#pragma unroll
    for (int i = 0; i < 16; ++i)
        ((float4*)ws_)[i * 256 + t] = ((const float4*)W)[i * 256 + t];

    int rpb = (((n + (int)gridDim.x - 1) / (int)gridDim.x) + 31) & ~31;
    int rowStart = blockIdx.x * rpb;
    int rowEnd = min(n, rowStart + rpb);
    int rg = t >> 5, cg = t & 31;
    float4 bv = make_float4(0.f, 0.f, 0.f, 0.f);
    if (bias) bv = ((const float4*)bias)[cg];
    float4 as4 = make_float4(0.f, 0.f, 0.f, 0.f), ad4 = as4;
    if (FUSE_AL) {
        as4 = ((const float4*)asrc)[cg];
        ad4 = ((const float4*)adst)[cg];
    }
    __syncthreads();

    for (int r0 = rowStart; r0 < rowEnd; r0 += 32) {
#pragma unroll
        for (int i = 0; i < 4; ++i) {
            int idx = i * 256 + t;
            int row = idx >> 5, col4 = idx & 31;
            int gr = r0 + row;
            float4 v = make_float4(0.f, 0.f, 0.f, 0.f);
            if (gr < n) v = ((const float4*)(A + (size_t)gr * 128))[col4];
            ((float4*)xs)[idx] = v;
        }
        __syncthreads();
        float acc[4][4];
#pragma unroll
        for (int i = 0; i < 4; ++i)
#pragma unroll
            for (int j = 0; j < 4; ++j) acc[i][j] = 0.f;

        const float* xb = xs + rg * 4 * 128;
        const float* wb = ws_ + cg * 4;
#pragma unroll 4
        for (int k4 = 0; k4 < 32; ++k4) {
            float4 xv[4], wv[4];
#pragma unroll
            for (int i = 0; i < 4; ++i) xv[i] = *(const float4*)(xb + i * 128 + k4 * 4);
#pragma unroll
            for (int kk = 0; kk < 4; ++kk) wv[kk] = *(const float4*)(wb + (k4 * 4 + kk) * 128);
#pragma unroll
            for (int i = 0; i < 4; ++i) {
                float x0 = xv[i].x, x1 = xv[i].y, x2 = xv[i].z, x3 = xv[i].w;
                acc[i][0] += x0 * wv[0].x + x1 * wv[1].x + x2 * wv[2].x + x3 * wv[3].x;
                acc[i][1] += x0 * wv[0].y + x1 * wv[1].y + x2 * wv[2].y + x3 * wv[3].y;
                acc[i][2] += x0 * wv[0].z + x1 * wv[1].z + x2 * wv[2].z + x3 * wv[3].z;
                acc[i][3] += x0 * wv[0].w + x1 * wv[1].w + x2 * wv[2].w + x3 * wv[3].w;
            }
        }
#pragma unroll
        for (int i = 0; i < 4; ++i) {
            int r = r0 + rg * 4 + i;
            if (r < n) {
                float4 o = make_float4(acc[i][0] + bv.x, acc[i][1] + bv.y,
                                       acc[i][2] + bv.z, acc[i][3] + bv.w);
                *(float4*)(out + (size_t)r * 128 + cg * 4) = o;
            }
        }
        if (FUSE_AL) {
            // head of this thread's 4 cols = cg>>3; reduce over the 8 cg-lanes of the head
#pragma unroll
            for (int i = 0; i < 4; ++i) {
                float ps = acc[i][0] * as4.x + acc[i][1] * as4.y +
                           acc[i][2] * as4.z + acc[i][3] * as4.w;
                float pd = acc[i][0] * ad4.x + acc[i][1] * ad4.y +
                           acc[i][2] * ad4.z + acc[i][3] * ad4.w;
                ps += __shfl_xor(ps, 1); ps += __shfl_xor(ps, 2); ps += __shfl_xor(ps, 4);
                pd += __shfl_xor(pd, 1); pd += __shfl_xor(pd, 2); pd += __shfl_xor(pd, 4);
                int r = r0 + rg * 4 + i;
                if ((cg & 7) == 0 && r < n) {
                    int hd = cg >> 3;
                    als[r * 4 + hd] = ps;
                    ald[r * 4 + hd] = pd;
                }
            }
        }
        __syncthreads();
    }
}

// ----------------- GAT aggregation: one wave per dst node, single pass (no max-shift),
// 4-wide unrolled gathers for memory-level parallelism -----------------
template <bool CONCAT>
__global__ void agg_kernel(const float* __restrict__ hp, const float* __restrict__ als,
                           const float* __restrict__ ald_, const int* __restrict__ rowp,
                           const int* __restrict__ col, const float* __restrict__ bias,
                           float* __restrict__ out, int n) {
    int wid = (blockIdx.x * blockDim.x + threadIdx.x) >> 6;
    if (wid >= n) return;
    int lane = threadIdx.x & 63;
    int d = wid;
    int h = lane >> 4;  // head of this lane's 2 channels
    int c2 = lane * 2;  // channel base 0..126
    float aldv = ald_[d * 4 + h];
    float eself = __expf(lrelu(als[d * 4 + h] + aldv));
    float2 v = *(const float2*)(hp + (size_t)d * 128 + c2);
    float a0 = eself * v.x, a1 = eself * v.y;
    float esum = eself;
    int p = rowp[d], end = rowp[d + 1];
    for (; p + 4 <= end; p += 4) {
        int s0 = col[p], s1 = col[p + 1], s2 = col[p + 2], s3 = col[p + 3];
        float q0 = als[s0 * 4 + h];
        float q1 = als[s1 * 4 + h];
        float q2 = als[s2 * 4 + h];
        float q3 = als[s3 * 4 + h];
        float2 u0 = *(const float2*)(hp + (size_t)s0 * 128 + c2);
        float2 u1 = *(const float2*)(hp + (size_t)s1 * 128 + c2);
        float2 u2 = *(const float2*)(hp + (size_t)s2 * 128 + c2);
        float2 u3 = *(const float2*)(hp + (size_t)s3 * 128 + c2);
        float e0 = __expf(lrelu(q0 + aldv));
        float e1 = __expf(lrelu(q1 + aldv));
        float e2 = __expf(lrelu(q2 + aldv));
        float e3 = __expf(lrelu(q3 + aldv));
        a0 += e0 * u0.x + e1 * u1.x + e2 * u2.x + e3 * u3.x;
        a1 += e0 * u0.y + e1 * u1.y + e2 * u2.y + e3 * u3.y;
        esum += e0 + e1 + e2 + e3;
    }
    for (; p < end; ++p) {
        int s = col[p];
        float e = __expf(lrelu(als[s * 4 + h] + aldv));
        float2 u = *(const float2*)(hp + (size_t)s * 128 + c2);
        a0 += e * u.x;
        a1 += e * u.y;
        esum += e;
    }
    float inv = 1.f / (esum + 1e-16f);
    a0 *= inv;
    a1 *= inv;
    if (CONCAT) {
        a0 = elu1(a0 + bias[c2]);
        a1 = elu1(a1 + bias[c2 + 1]);
        *(float2*)(out + (size_t)d * 128 + c2) = make_float2(a0, a1);
    } else {
        // mean over heads: combine lanes {l, l^16, l^32, l^48}
        a0 += __shfl_xor(a0, 16); a0 += __shfl_xor(a0, 32);
        a1 += __shfl_xor(a1, 16); a1 += __shfl_xor(a1, 32);
        if (lane < 16) {
            float r0 = elu1(a0 * 0.25f + bias[c2]);
            float r1 = elu1(a1 * 0.25f + bias[c2 + 1]);
            *(float2*)(out + (size_t)d * 32 + c2) = make_float2(r0, r1);
        }
    }
}

// ----------------- mean pool per batch segment (batch sorted) -----------------
__global__ void pool_kernel(const float* __restrict__ h2, const int* __restrict__ batch,
                            int n, float* __restrict__ pooled) {
    int b = blockIdx.x;
    __shared__ int sb[2];
    if (threadIdx.x == 0) {
        int lo = 0, hi = n;
        while (lo < hi) { int mid = (lo + hi) >> 1; if (batch[mid] < b) lo = mid + 1; else hi = mid; }
        sb[0] = lo;
        int lo2 = lo, hi2 = n;
        while (lo2 < hi2) { int mid = (lo2 + hi2) >> 1; if (batch[mid] < b + 1) lo2 = mid + 1; else hi2 = mid; }
        sb[1] = lo2;
    }
    __syncthreads();
    int lo = sb[0], hi = sb[1];
    int c = threadIdx.x & 31, g = threadIdx.x >> 5; // 8 groups of 32
    float acc = 0.f;
    for (int i = lo + g; i < hi; i += 8) acc += h2[(size_t)i * 32 + c];
    __shared__ float red[8][32];
    red[g][c] = acc;
    __syncthreads();
    if (threadIdx.x < 32) {
        float s = 0.f;
#pragma unroll
        for (int g2 = 0; g2 < 8; ++g2) s += red[g2][threadIdx.x];
        float cnt = (float)(hi - lo);
        pooled[b * 32 + threadIdx.x] = s / fmaxf(cnt, 1.f);
    }
}

// ----------------- final_proj + MLP head, one block per batch row -----------------
__global__ void mlp_kernel(const float* __restrict__ pooled, const float* __restrict__ w_fp,
                           const float* __restrict__ b_fp, const float* __restrict__ w_m1,
                           const float* __restrict__ b_m1, const float* __restrict__ w_m2,
                           const float* __restrict__ b_m2, float* __restrict__ out) {
    int b = blockIdx.x, t = threadIdx.x; // 128 threads
    __shared__ float sp[32], so[128];
    if (t < 32) sp[t] = pooled[b * 32 + t];
    __syncthreads();
    float o = b_fp[t];
#pragma unroll 8
    for (int k = 0; k < 32; ++k) o += sp[k] * w_fp[k * 128 + t];
    so[t] = o;
    __syncthreads();
    if (t < 64) {
        float hm = b_m1[t];
        for (int c = 0; c < 128; ++c) hm += so[c] * w_m1[c * 64 + t];
        float v = fmaxf(hm, 0.f) * w_m2[t];
#pragma unroll
        for (int offd = 32; offd > 0; offd >>= 1) v += __shfl_down(v, offd);
        if (t == 0) out[b] = v + b_m2[0];
    }
}

extern "C" void kernel_launch(void* const* d_in, const int* in_sizes, int n_in,
                              void* d_out, int out_size, void* d_ws, size_t ws_size,
                              hipStream_t stream) {
    const float* x = (const float*)d_in[0];
    const int* ei = (const int*)d_in[1];
    const int* batch = (const int*)d_in[2];
    const float* w_in = (const float*)d_in[3];
    const float* b_in = (const float*)d_in[4];
    const float* w[3] = {(const float*)d_in[5], (const float*)d_in[9], (const float*)d_in[13]};
    const float* asrc[3] = {(const float*)d_in[6], (const float*)d_in[10], (const float*)d_in[14]};
    const float* adst[3] = {(const float*)d_in[7], (const float*)d_in[11], (const float*)d_in[15]};
    const float* bb[3] = {(const float*)d_in[8], (const float*)d_in[12], (const float*)d_in[16]};
    const float* w_fp = (const float*)d_in[17];
    const float* b_fp = (const float*)d_in[18];
    const float* w_m1 = (const float*)d_in[19];
    const float* b_m1 = (const float*)d_in[20];
    const float* w_m2 = (const float*)d_in[21];
    const float* b_m2 = (const float*)d_in[22];

    int n = in_sizes[0] / 128;
    int e = in_sizes[1] / 2;
    int B = out_size;

    char* wsb = (char*)d_ws;
    size_t off = 0;
    auto alloc = [&](size_t bytes) -> void* {
        void* p = wsb + off;
        off += (bytes + 255) & ~(size_t)255;
        return p;
    };
    float* hA = (float*)alloc((size_t)n * 128 * 4);
    float* hB = (float*)alloc((size_t)n * 128 * 4);
    float* als = (float*)alloc((size_t)n * 4 * 4);
    float* ald = (float*)alloc((size_t)n * 4 * 4);
    int* deg = (int*)alloc((size_t)n * 4);       // reused as cursor
    int* rowp = (int*)alloc((size_t)(n + 1) * 4);
    int* col = (int*)alloc((size_t)e * 4);
    int* bsums = (int*)alloc(4096);
    float* pooled = (float*)alloc((size_t)B * 32 * 4);

    const int* srcp = ei;
    const int* dstp = ei + e;

    // CSR by dst (graph shared by all 3 layers)
    hipMemsetAsync(deg, 0, (size_t)n * 4, stream);
    hist_kernel<<<(e + 255) / 256, 256, 0, stream>>>(dstp, e, deg);
    int nb = (n + 2047) / 2048;
    scan1_kernel<<<nb, 256, 0, stream>>>(deg, n, rowp, bsums);
    scan2_kernel<<<1, 64, 0, stream>>>(bsums, nb);
    scan3_kernel<<<(n + 256) / 256, 256, 0, stream>>>(rowp, bsums, n, e, deg);
    fill_kernel<<<(e + 255) / 256, 256, 0, stream>>>(srcp, dstp, e, deg, col);

    // input projection (no attention logits needed)
    gemm128_kernel<false><<<512, 256, 0, stream>>>(x, w_in, b_in, hA, n,
                                                   nullptr, nullptr, nullptr, nullptr);

    // 3 GAT layers: gemm hA->hB (+fused al), aggregate hB->hA
    for (int L = 0; L < 3; ++L) {
        gemm128_kernel<true><<<512, 256, 0, stream>>>(hA, w[L], nullptr, hB, n,
                                                      asrc[L], adst[L], als, ald);
        int gridAgg = (n + 3) / 4;
        if (L < 2)
            agg_kernel<true><<<gridAgg, 256, 0, stream>>>(hB, als, ald, rowp, col, bb[L], hA, n);
        else
            agg_kernel<false><<<gridAgg, 256, 0, stream>>>(hB, als, ald, rowp, col, bb[L], hA, n);
    }

    // pooling over batch segments, then MLP head
    pool_kernel<<<B, 256, 0, stream>>>(hA, batch, n, pooled);
    mlp_kernel<<<B, 128, 0, stream>>>(pooled, w_fp, b_fp, w_m1, b_m1, w_m2, b_m2, (float*)d_out);
}

// Round 3
// 410.744 us; speedup vs baseline: 1.8808x; 1.3843x over previous
//
#include <hip/hip_runtime.h>

#define NEG 0.2f

typedef short s16x8 __attribute__((ext_vector_type(8)));
typedef float f32x4 __attribute__((ext_vector_type(4)));

__device__ __forceinline__ float lrelu(float x) { return x >= 0.f ? x : NEG * x; }
__device__ __forceinline__ float elu1(float x) { return x > 0.f ? x : __expf(x) - 1.f; }

__device__ __forceinline__ ushort bf16rn(float f) {
    unsigned u = __float_as_uint(f);
    u += 0x7fffu + ((u >> 16) & 1u);
    return (ushort)(u >> 16);
}
__device__ __forceinline__ float bf16tof(ushort h) {
    return __uint_as_float(((unsigned)h) << 16);
}

// ----------------- CSR build -----------------
__global__ void hist_kernel(const int* __restrict__ dst, int e, int* __restrict__ deg) {
    int i = blockIdx.x * blockDim.x + threadIdx.x;
    if (i < e) atomicAdd(&deg[dst[i]], 1);
}

__device__ __forceinline__ int waveIncScanI(int v, int lane) {
#pragma unroll
    for (int off = 1; off < 64; off <<= 1) {
        int u = __shfl_up(v, off);
        if (lane >= off) v += u;
    }
    return v;
}

__global__ void scan1_kernel(const int* __restrict__ deg, int n,
                             int* __restrict__ rowp, int* __restrict__ bsums) {
    int t = threadIdx.x;
    int base = blockIdx.x * 2048 + t * 8;
    int vals[8];
    int sum = 0;
#pragma unroll
    for (int i = 0; i < 8; ++i) {
        int idx = base + i;
        int v = (idx < n) ? deg[idx] : 0;
        vals[i] = sum;
        sum += v;
    }
    int lane = t & 63, w = t >> 6;
    int inc = waveIncScanI(sum, lane);
    __shared__ int wsums[4];
    if (lane == 63) wsums[w] = inc;
    __syncthreads();
    int wpre = 0;
#pragma unroll
    for (int i = 0; i < 3; ++i) wpre += (i < w) ? wsums[i] : 0;
    int exc = wpre + inc - sum;
#pragma unroll
    for (int i = 0; i < 8; ++i) {
        int idx = base + i;
        if (idx < n) rowp[idx] = exc + vals[i];
    }
    if (t == 255) bsums[blockIdx.x] = wpre + inc;
}

__global__ void scan2_kernel(int* bsums, int nb) {
    int lane = threadIdx.x & 63;
    int run = 0;
    for (int base = 0; base < nb; base += 64) {
        int i = base + lane;
        int v = (i < nb) ? bsums[i] : 0;
        int inc = waveIncScanI(v, lane);
        if (i < nb) bsums[i] = run + inc - v;
        run += __shfl(inc, 63);
    }
}

__global__ void scan3_kernel(int* __restrict__ rowp, const int* __restrict__ bsums,
                             int n, int total, int* __restrict__ cursor) {
    int i = blockIdx.x * blockDim.x + threadIdx.x;
    if (i < n) {
        int v = rowp[i] + bsums[i >> 11];
        rowp[i] = v;
        cursor[i] = v;
    } else if (i == n) {
        rowp[n] = total;
    }
}

__global__ void fill_kernel(const int* __restrict__ src, const int* __restrict__ dst, int e,
                            int* __restrict__ cursor, int* __restrict__ col) {
    int i = blockIdx.x * blockDim.x + threadIdx.x;
    if (i < e) {
        int pos = atomicAdd(&cursor[dst[i]], 1);
        col[pos] = src[i];
    }
}

// ----------------- W pre-pack: fp32 [128][128] -> bf16 hi/lo in MFMA B-frag order
// layout: [layer][kt(4)][ntg(8)][lane(64)][j(8)]  (lane l holds W[kt*32+(l>>4)*8+j][ntg*16+(l&15)])
__global__ void wpack_kernel(const float* __restrict__ w0, const float* __restrict__ w1,
                             const float* __restrict__ w2, const float* __restrict__ w3,
                             ushort* __restrict__ whi, ushort* __restrict__ wlo) {
    int idx = blockIdx.x * 256 + threadIdx.x; // 4*16384
    int layer = idx >> 14, e = idx & 16383;
    const float* W = layer == 0 ? w0 : layer == 1 ? w1 : layer == 2 ? w2 : w3;
    int k = e >> 7, c = e & 127;
    float w = W[e];
    ushort hi = bf16rn(w);
    ushort lo = bf16rn(w - bf16tof(hi));
    int kt = k >> 5, kk = k & 31, j = kk & 7;
    int ln = ((kk >> 3) << 4) | (c & 15);
    int ntg = c >> 4;
    int pos = (layer << 14) + (((kt << 3) + ntg) * 64 + ln) * 8 + j;
    whi[pos] = hi;
    wlo[pos] = lo;
}

// ----------------- MFMA split-bf16 GEMM: out[n,128] = A[n,128] @ W[128,128]
// 512 threads = 8 waves; wave w: head/ntile-pair = w&3 (32 cols), row-half = w>>2 (16 rows of a
// 32-row tile). W hi/lo frags register-resident. Optional bias; optional fused attention logits.
template <bool BIAS, bool AL>
__global__ __launch_bounds__(512, 4) void gemm_mfma_kernel(
    const float* __restrict__ A, const ushort* __restrict__ whi, const ushort* __restrict__ wlo,
    const float* __restrict__ bias, float* __restrict__ out, int n, int ntiles,
    const float* __restrict__ asrc, const float* __restrict__ adst,
    float* __restrict__ als, float* __restrict__ ald) {
    __shared__ s16x8 ahi[2][4][64];
    __shared__ s16x8 alo[2][4][64];
    int t = threadIdx.x;
    int wid = t >> 6, lane = t & 63;
    int ntp = wid & 3;    // head
    int mhalf = wid >> 2; // which 16-row half

    // register-resident W fragments (this wave's 2 n-tiles x 4 k-tiles, hi+lo)
    const s16x8* wph = (const s16x8*)whi;
    const s16x8* wpl = (const s16x8*)wlo;
    s16x8 wh[4][2], wl[4][2];
#pragma unroll
    for (int kt = 0; kt < 4; ++kt)
#pragma unroll
        for (int j = 0; j < 2; ++j) {
            int ntg = ntp * 2 + j;
            wh[kt][j] = wph[((kt << 3) + ntg) * 64 + lane];
            wl[kt][j] = wpl[((kt << 3) + ntg) * 64 + lane];
        }

    int c0 = ntp * 32 + (lane & 15);
    int c1 = c0 + 16;
    float bv0 = 0.f, bv1 = 0.f;
    if (BIAS) { bv0 = bias[c0]; bv1 = bias[c1]; }
    float as0 = 0.f, as1 = 0.f, ad0 = 0.f, ad1 = 0.f;
    if (AL) {
        as0 = asrc[ntp * 32 + (lane & 15)];
        as1 = asrc[ntp * 32 + 16 + (lane & 15)];
        ad0 = adst[ntp * 32 + (lane & 15)];
        ad1 = adst[ntp * 32 + 16 + (lane & 15)];
    }

    // staging map: thread t -> (row=t>>4 of tile, koct=t&15); one s16x8 (8 k's) per array
    int srow = t >> 4, skoct = t & 15;
    int smh = srow >> 4, skt = skoct >> 2;
    int sln = ((skoct & 3) << 4) | (srow & 15);

    for (int tile = blockIdx.x; tile < ntiles; tile += gridDim.x) {
        int r0 = tile * 32;
        // ---- stage A tile (32 rows) as bf16 hi/lo fragments ----
        {
            int gr = r0 + srow;
            float4 v0 = make_float4(0.f, 0.f, 0.f, 0.f), v1 = v0;
            if (gr < n) {
                const float4* rp = (const float4*)(A + (size_t)gr * 128 + skoct * 8);
                v0 = rp[0];
                v1 = rp[1];
            }
            float f[8] = {v0.x, v0.y, v0.z, v0.w, v1.x, v1.y, v1.z, v1.w};
            s16x8 hi, lo;
#pragma unroll
            for (int j = 0; j < 8; ++j) {
                ushort h = bf16rn(f[j]);
                hi[j] = (short)h;
                lo[j] = (short)bf16rn(f[j] - bf16tof(h));
            }
            ahi[smh][skt][sln] = hi;
            alo[smh][skt][sln] = lo;
        }
        __syncthreads();

        // ---- MFMA K-loop ----
        f32x4 acc0 = {0.f, 0.f, 0.f, 0.f};
        f32x4 acc1 = {0.f, 0.f, 0.f, 0.f};
#pragma unroll
        for (int kt = 0; kt < 4; ++kt) {
            s16x8 ah = ahi[mhalf][kt][lane];
            s16x8 al = alo[mhalf][kt][lane];
            acc0 = __builtin_amdgcn_mfma_f32_16x16x32_bf16(ah, wh[kt][0], acc0, 0, 0, 0);
            acc0 = __builtin_amdgcn_mfma_f32_16x16x32_bf16(ah, wl[kt][0], acc0, 0, 0, 0);
            acc0 = __builtin_amdgcn_mfma_f32_16x16x32_bf16(al, wh[kt][0], acc0, 0, 0, 0);
            acc1 = __builtin_amdgcn_mfma_f32_16x16x32_bf16(ah, wh[kt][1], acc1, 0, 0, 0);
            acc1 = __builtin_amdgcn_mfma_f32_16x16x32_bf16(ah, wl[kt][1], acc1, 0, 0, 0);
            acc1 = __builtin_amdgcn_mfma_f32_16x16x32_bf16(al, wh[kt][1], acc1, 0, 0, 0);
        }

        // ---- epilogue: C/D layout col=lane&15, row=(lane>>4)*4+i ----
        int rbase = r0 + mhalf * 16 + (lane >> 4) * 4;
#pragma unroll
        for (int i = 0; i < 4; ++i) {
            int r = rbase + i;
            if (r < n) {
                out[(size_t)r * 128 + c0] = acc0[i] + bv0;
                out[(size_t)r * 128 + c1] = acc1[i] + bv1;
            }
        }
        if (AL) {
#pragma unroll
            for (int i = 0; i < 4; ++i) {
                float ps = acc0[i] * as0 + acc1[i] * as1;
                float pd = acc0[i] * ad0 + acc1[i] * ad1;
                ps += __shfl_xor(ps, 1); ps += __shfl_xor(ps, 2);
                ps += __shfl_xor(ps, 4); ps += __shfl_xor(ps, 8);
                pd += __shfl_xor(pd, 1); pd += __shfl_xor(pd, 2);
                pd += __shfl_xor(pd, 4); pd += __shfl_xor(pd, 8);
                int r = rbase + i;
                if ((lane & 15) == 0 && r < n) {
                    als[r * 4 + ntp] = ps;
                    ald[r * 4 + ntp] = pd;
                }
            }
        }
        __syncthreads();
    }
}

// ----------------- GAT aggregation: one wave per dst node, single pass (no max-shift),
// 4-wide unrolled gathers for memory-level parallelism -----------------
template <bool CONCAT>
__global__ void agg_kernel(const float* __restrict__ hp, const float* __restrict__ als,
                           const float* __restrict__ ald_, const int* __restrict__ rowp,
                           const int* __restrict__ col, const float* __restrict__ bias,
                           float* __restrict__ out, int n) {
    int wid = (blockIdx.x * blockDim.x + threadIdx.x) >> 6;
    if (wid >= n) return;
    int lane = threadIdx.x & 63;
    int d = wid;
    int h = lane >> 4;  // head of this lane's 2 channels
    int c2 = lane * 2;  // channel base 0..126
    float aldv = ald_[d * 4 + h];
    float eself = __expf(lrelu(als[d * 4 + h] + aldv));
    float2 v = *(const float2*)(hp + (size_t)d * 128 + c2);
    float a0 = eself * v.x, a1 = eself * v.y;
    float esum = eself;
    int p = rowp[d], end = rowp[d + 1];
    for (; p + 4 <= end; p += 4) {
        int s0 = col[p], s1 = col[p + 1], s2 = col[p + 2], s3 = col[p + 3];
        float q0 = als[s0 * 4 + h];
        float q1 = als[s1 * 4 + h];
        float q2 = als[s2 * 4 + h];
        float q3 = als[s3 * 4 + h];
        float2 u0 = *(const float2*)(hp + (size_t)s0 * 128 + c2);
        float2 u1 = *(const float2*)(hp + (size_t)s1 * 128 + c2);
        float2 u2 = *(const float2*)(hp + (size_t)s2 * 128 + c2);
        float2 u3 = *(const float2*)(hp + (size_t)s3 * 128 + c2);
        float e0 = __expf(lrelu(q0 + aldv));
        float e1 = __expf(lrelu(q1 + aldv));
        float e2 = __expf(lrelu(q2 + aldv));
        float e3 = __expf(lrelu(q3 + aldv));
        a0 += e0 * u0.x + e1 * u1.x + e2 * u2.x + e3 * u3.x;
        a1 += e0 * u0.y + e1 * u1.y + e2 * u2.y + e3 * u3.y;
        esum += e0 + e1 + e2 + e3;
    }
    for (; p < end; ++p) {
        int s = col[p];
        float e = __expf(lrelu(als[s * 4 + h] + aldv));
        float2 u = *(const float2*)(hp + (size_t)s * 128 + c2);
        a0 += e * u.x;
        a1 += e * u.y;
        esum += e;
    }
    float inv = 1.f / (esum + 1e-16f);
    a0 *= inv;
    a1 *= inv;
    if (CONCAT) {
        a0 = elu1(a0 + bias[c2]);
        a1 = elu1(a1 + bias[c2 + 1]);
        *(float2*)(out + (size_t)d * 128 + c2) = make_float2(a0, a1);
    } else {
        // mean over heads: combine lanes {l, l^16, l^32, l^48}
        a0 += __shfl_xor(a0, 16); a0 += __shfl_xor(a0, 32);
        a1 += __shfl_xor(a1, 16); a1 += __shfl_xor(a1, 32);
        if (lane < 16) {
            float r0 = elu1(a0 * 0.25f + bias[c2]);
            float r1 = elu1(a1 * 0.25f + bias[c2 + 1]);
            *(float2*)(out + (size_t)d * 32 + c2) = make_float2(r0, r1);
        }
    }
}

// ----------------- mean pool per batch segment (batch sorted) -----------------
__global__ void pool_kernel(const float* __restrict__ h2, const int* __restrict__ batch,
                            int n, float* __restrict__ pooled) {
    int b = blockIdx.x;
    __shared__ int sb[2];
    if (threadIdx.x == 0) {
        int lo = 0, hi = n;
        while (lo < hi) { int mid = (lo + hi) >> 1; if (batch[mid] < b) lo = mid + 1; else hi = mid; }
        sb[0] = lo;
        int lo2 = lo, hi2 = n;
        while (lo2 < hi2) { int mid = (lo2 + hi2) >> 1; if (batch[mid] < b + 1) lo2 = mid + 1; else hi2 = mid; }
        sb[1] = lo2;
    }
    __syncthreads();
    int lo = sb[0], hi = sb[1];
    int c = threadIdx.x & 31, g = threadIdx.x >> 5; // 8 groups of 32
    float acc = 0.f;
    for (int i = lo + g; i < hi; i += 8) acc += h2[(size_t)i * 32 + c];
    __shared__ float red[8][32];
    red[g][c] = acc;
    __syncthreads();
    if (threadIdx.x < 32) {
        float s = 0.f;
#pragma unroll
        for (int g2 = 0; g2 < 8; ++g2) s += red[g2][threadIdx.x];
        float cnt = (float)(hi - lo);
        pooled[b * 32 + threadIdx.x] = s / fmaxf(cnt, 1.f);
    }
}

// ----------------- final_proj + MLP head, one block per batch row -----------------
__global__ void mlp_kernel(const float* __restrict__ pooled, const float* __restrict__ w_fp,
                           const float* __restrict__ b_fp, const float* __restrict__ w_m1,
                           const float* __restrict__ b_m1, const float* __restrict__ w_m2,
                           const float* __restrict__ b_m2, float* __restrict__ out) {
    int b = blockIdx.x, t = threadIdx.x; // 128 threads
    __shared__ float sp[32], so[128];
    if (t < 32) sp[t] = pooled[b * 32 + t];
    __syncthreads();
    float o = b_fp[t];
#pragma unroll 8
    for (int k = 0; k < 32; ++k) o += sp[k] * w_fp[k * 128 + t];
    so[t] = o;
    __syncthreads();
    if (t < 64) {
        float hm = b_m1[t];
        for (int c = 0; c < 128; ++c) hm += so[c] * w_m1[c * 64 + t];
        float v = fmaxf(hm, 0.f) * w_m2[t];
#pragma unroll
        for (int offd = 32; offd > 0; offd >>= 1) v += __shfl_down(v, offd);
        if (t == 0) out[b] = v + b_m2[0];
    }
}

extern "C" void kernel_launch(void* const* d_in, const int* in_sizes, int n_in,
                              void* d_out, int out_size, void* d_ws, size_t ws_size,
                              hipStream_t stream) {
    const float* x = (const float*)d_in[0];
    const int* ei = (const int*)d_in[1];
    const int* batch = (const int*)d_in[2];
    const float* w_in = (const float*)d_in[3];
    const float* b_in = (const float*)d_in[4];
    const float* w[3] = {(const float*)d_in[5], (const float*)d_in[9], (const float*)d_in[13]};
    const float* asrc[3] = {(const float*)d_in[6], (const float*)d_in[10], (const float*)d_in[14]};
    const float* adst[3] = {(const float*)d_in[7], (const float*)d_in[11], (const float*)d_in[15]};
    const float* bb[3] = {(const float*)d_in[8], (const float*)d_in[12], (const float*)d_in[16]};
    const float* w_fp = (const float*)d_in[17];
    const float* b_fp = (const float*)d_in[18];
    const float* w_m1 = (const float*)d_in[19];
    const float* b_m1 = (const float*)d_in[20];
    const float* w_m2 = (const float*)d_in[21];
    const float* b_m2 = (const float*)d_in[22];

    int n = in_sizes[0] / 128;
    int e = in_sizes[1] / 2;
    int B = out_size;

    char* wsb = (char*)d_ws;
    size_t off = 0;
    auto alloc = [&](size_t bytes) -> void* {
        void* p = wsb + off;
        off += (bytes + 255) & ~(size_t)255;
        return p;
    };
    float* hA = (float*)alloc((size_t)n * 128 * 4);
    float* hB = (float*)alloc((size_t)n * 128 * 4);
    float* als = (float*)alloc((size_t)n * 4 * 4);
    float* ald = (float*)alloc((size_t)n * 4 * 4);
    int* deg = (int*)alloc((size_t)n * 4);       // reused as cursor
    int* rowp = (int*)alloc((size_t)(n + 1) * 4);
    int* col = (int*)alloc((size_t)e * 4);
    int* bsums = (int*)alloc(4096);
    float* pooled = (float*)alloc((size_t)B * 32 * 4);
    ushort* whi = (ushort*)alloc((size_t)4 * 16384 * 2);
    ushort* wlo = (ushort*)alloc((size_t)4 * 16384 * 2);

    const int* srcp = ei;
    const int* dstp = ei + e;

    // CSR by dst (graph shared by all 3 layers)
    hipMemsetAsync(deg, 0, (size_t)n * 4, stream);
    hist_kernel<<<(e + 255) / 256, 256, 0, stream>>>(dstp, e, deg);
    int nb = (n + 2047) / 2048;
    scan1_kernel<<<nb, 256, 0, stream>>>(deg, n, rowp, bsums);
    scan2_kernel<<<1, 64, 0, stream>>>(bsums, nb);
    scan3_kernel<<<(n + 256) / 256, 256, 0, stream>>>(rowp, bsums, n, e, deg);
    fill_kernel<<<(e + 255) / 256, 256, 0, stream>>>(srcp, dstp, e, deg, col);

    // pre-pack all 4 weight matrices into bf16 hi/lo MFMA fragment order
    wpack_kernel<<<256, 256, 0, stream>>>(w_in, w[0], w[1], w[2], whi, wlo);

    int ntiles = (n + 31) / 32;
    int gblk = ntiles < 1024 ? ntiles : 1024;

    // input projection (bias, no attention logits)
    gemm_mfma_kernel<true, false><<<gblk, 512, 0, stream>>>(
        x, whi, wlo, b_in, hA, n, ntiles, nullptr, nullptr, nullptr, nullptr);

    // 3 GAT layers: mfma gemm hA->hB (+fused al), aggregate hB->hA
    for (int L = 0; L < 3; ++L) {
        gemm_mfma_kernel<false, true><<<gblk, 512, 0, stream>>>(
            hA, whi + (size_t)(L + 1) * 16384, wlo + (size_t)(L + 1) * 16384, nullptr, hB, n,
            ntiles, asrc[L], adst[L], als, ald);
        int gridAgg = (n + 3) / 4;
        if (L < 2)
            agg_kernel<true><<<gridAgg, 256, 0, stream>>>(hB, als, ald, rowp, col, bb[L], hA, n);
        else
            agg_kernel<false><<<gridAgg, 256, 0, stream>>>(hB, als, ald, rowp, col, bb[L], hA, n);
    }

    // pooling over batch segments, then MLP head
    pool_kernel<<<B, 256, 0, stream>>>(hA, batch, n, pooled);
    mlp_kernel<<<B, 128, 0, stream>>>(pooled, w_fp, b_fp, w_m1, b_m1, w_m2, b_m2, (float*)d_out);
}

// Round 4
// 355.545 us; speedup vs baseline: 2.1728x; 1.1553x over previous
//
#include <hip/hip_runtime.h>

#define NEG 0.2f

typedef short s16x8 __attribute__((ext_vector_type(8)));
typedef float f32x4 __attribute__((ext_vector_type(4)));

__device__ __forceinline__ float lrelu(float x) { return x >= 0.f ? x : NEG * x; }
__device__ __forceinline__ float elu1(float x) { return x > 0.f ? x : __expf(x) - 1.f; }

__device__ __forceinline__ ushort bf16rn(float f) {
    unsigned u = __float_as_uint(f);
    u += 0x7fffu + ((u >> 16) & 1u);
    return (ushort)(u >> 16);
}
__device__ __forceinline__ float bf16tof(ushort h) {
    return __uint_as_float(((unsigned)h) << 16);
}

// ----------------- CSR build -----------------
__global__ void hist_kernel(const int* __restrict__ dst, int e, int* __restrict__ deg) {
    int i = blockIdx.x * blockDim.x + threadIdx.x;
    if (i < e) atomicAdd(&deg[dst[i]], 1);
}

__device__ __forceinline__ int waveIncScanI(int v, int lane) {
#pragma unroll
    for (int off = 1; off < 64; off <<= 1) {
        int u = __shfl_up(v, off);
        if (lane >= off) v += u;
    }
    return v;
}

__global__ void scan1_kernel(const int* __restrict__ deg, int n,
                             int* __restrict__ rowp, int* __restrict__ bsums) {
    int t = threadIdx.x;
    int base = blockIdx.x * 2048 + t * 8;
    int vals[8];
    int sum = 0;
#pragma unroll
    for (int i = 0; i < 8; ++i) {
        int idx = base + i;
        int v = (idx < n) ? deg[idx] : 0;
        vals[i] = sum;
        sum += v;
    }
    int lane = t & 63, w = t >> 6;
    int inc = waveIncScanI(sum, lane);
    __shared__ int wsums[4];
    if (lane == 63) wsums[w] = inc;
    __syncthreads();
    int wpre = 0;
#pragma unroll
    for (int i = 0; i < 3; ++i) wpre += (i < w) ? wsums[i] : 0;
    int exc = wpre + inc - sum;
#pragma unroll
    for (int i = 0; i < 8; ++i) {
        int idx = base + i;
        if (idx < n) rowp[idx] = exc + vals[i];
    }
    if (t == 255) bsums[blockIdx.x] = wpre + inc;
}

__global__ void scan2_kernel(int* bsums, int nb) {
    int lane = threadIdx.x & 63;
    int run = 0;
    for (int base = 0; base < nb; base += 64) {
        int i = base + lane;
        int v = (i < nb) ? bsums[i] : 0;
        int inc = waveIncScanI(v, lane);
        if (i < nb) bsums[i] = run + inc - v;
        run += __shfl(inc, 63);
    }
}

__global__ void scan3_kernel(int* __restrict__ rowp, const int* __restrict__ bsums,
                             int n, int total, int* __restrict__ cursor) {
    int i = blockIdx.x * blockDim.x + threadIdx.x;
    if (i < n) {
        int v = rowp[i] + bsums[i >> 11];
        rowp[i] = v;
        cursor[i] = v;
    } else if (i == n) {
        rowp[n] = total;
    }
}

__global__ void fill_kernel(const int* __restrict__ src, const int* __restrict__ dst, int e,
                            int* __restrict__ cursor, int* __restrict__ col) {
    int i = blockIdx.x * blockDim.x + threadIdx.x;
    if (i < e) {
        int pos = atomicAdd(&cursor[dst[i]], 1);
        col[pos] = src[i];
    }
}

// ----------------- W pre-pack: fp32 [128][128] -> bf16 hi/lo in MFMA B-frag order
__global__ void wpack_kernel(const float* __restrict__ w0, const float* __restrict__ w1,
                             const float* __restrict__ w2, const float* __restrict__ w3,
                             ushort* __restrict__ whi, ushort* __restrict__ wlo) {
    int idx = blockIdx.x * 256 + threadIdx.x; // 4*16384
    int layer = idx >> 14, e = idx & 16383;
    const float* W = layer == 0 ? w0 : layer == 1 ? w1 : layer == 2 ? w2 : w3;
    int k = e >> 7, c = e & 127;
    float w = W[e];
    ushort hi = bf16rn(w);
    ushort lo = bf16rn(w - bf16tof(hi));
    int kt = k >> 5, kk = k & 31, j = kk & 7;
    int ln = ((kk >> 3) << 4) | (c & 15);
    int ntg = c >> 4;
    int pos = (layer << 14) + (((kt << 3) + ntg) * 64 + ln) * 8 + j;
    whi[pos] = hi;
    wlo[pos] = lo;
}

// ----------------- MFMA split-bf16 GEMM: out[n,128] = A[n,128] @ W[128,128]
// BF16OUT: store result rows as bf16 (feeds the gather-heavy aggregation).
template <bool BIAS, bool AL, bool BF16OUT>
__global__ __launch_bounds__(512, 4) void gemm_mfma_kernel(
    const float* __restrict__ A, const ushort* __restrict__ whi, const ushort* __restrict__ wlo,
    const float* __restrict__ bias, void* __restrict__ outv, int n, int ntiles,
    const float* __restrict__ asrc, const float* __restrict__ adst,
    float* __restrict__ als, float* __restrict__ ald) {
    __shared__ s16x8 ahi[2][4][64];
    __shared__ s16x8 alo[2][4][64];
    int t = threadIdx.x;
    int wid = t >> 6, lane = t & 63;
    int ntp = wid & 3;    // head / 32-col pair
    int mhalf = wid >> 2; // which 16-row half

    const s16x8* wph = (const s16x8*)whi;
    const s16x8* wpl = (const s16x8*)wlo;
    s16x8 wh[4][2], wl[4][2];
#pragma unroll
    for (int kt = 0; kt < 4; ++kt)
#pragma unroll
        for (int j = 0; j < 2; ++j) {
            int ntg = ntp * 2 + j;
            wh[kt][j] = wph[((kt << 3) + ntg) * 64 + lane];
            wl[kt][j] = wpl[((kt << 3) + ntg) * 64 + lane];
        }

    int c0 = ntp * 32 + (lane & 15);
    int c1 = c0 + 16;
    float bv0 = 0.f, bv1 = 0.f;
    if (BIAS) { bv0 = bias[c0]; bv1 = bias[c1]; }
    float as0 = 0.f, as1 = 0.f, ad0 = 0.f, ad1 = 0.f;
    if (AL) {
        as0 = asrc[ntp * 32 + (lane & 15)];
        as1 = asrc[ntp * 32 + 16 + (lane & 15)];
        ad0 = adst[ntp * 32 + (lane & 15)];
        ad1 = adst[ntp * 32 + 16 + (lane & 15)];
    }

    int srow = t >> 4, skoct = t & 15;
    int smh = srow >> 4, skt = skoct >> 2;
    int sln = ((skoct & 3) << 4) | (srow & 15);

    for (int tile = blockIdx.x; tile < ntiles; tile += gridDim.x) {
        int r0 = tile * 32;
        {
            int gr = r0 + srow;
            float4 v0 = make_float4(0.f, 0.f, 0.f, 0.f), v1 = v0;
            if (gr < n) {
                const float4* rp = (const float4*)(A + (size_t)gr * 128 + skoct * 8);
                v0 = rp[0];
                v1 = rp[1];
            }
            float f[8] = {v0.x, v0.y, v0.z, v0.w, v1.x, v1.y, v1.z, v1.w};
            s16x8 hi, lo;
#pragma unroll
            for (int j = 0; j < 8; ++j) {
                ushort h = bf16rn(f[j]);
                hi[j] = (short)h;
                lo[j] = (short)bf16rn(f[j] - bf16tof(h));
            }
            ahi[smh][skt][sln] = hi;
            alo[smh][skt][sln] = lo;
        }
        __syncthreads();

        f32x4 acc0 = {0.f, 0.f, 0.f, 0.f};
        f32x4 acc1 = {0.f, 0.f, 0.f, 0.f};
#pragma unroll
        for (int kt = 0; kt < 4; ++kt) {
            s16x8 ah = ahi[mhalf][kt][lane];
            s16x8 al = alo[mhalf][kt][lane];
            acc0 = __builtin_amdgcn_mfma_f32_16x16x32_bf16(ah, wh[kt][0], acc0, 0, 0, 0);
            acc0 = __builtin_amdgcn_mfma_f32_16x16x32_bf16(ah, wl[kt][0], acc0, 0, 0, 0);
            acc0 = __builtin_amdgcn_mfma_f32_16x16x32_bf16(al, wh[kt][0], acc0, 0, 0, 0);
            acc1 = __builtin_amdgcn_mfma_f32_16x16x32_bf16(ah, wh[kt][1], acc1, 0, 0, 0);
            acc1 = __builtin_amdgcn_mfma_f32_16x16x32_bf16(ah, wl[kt][1], acc1, 0, 0, 0);
            acc1 = __builtin_amdgcn_mfma_f32_16x16x32_bf16(al, wh[kt][1], acc1, 0, 0, 0);
        }

        int rbase = r0 + mhalf * 16 + (lane >> 4) * 4;
#pragma unroll
        for (int i = 0; i < 4; ++i) {
            int r = rbase + i;
            if (r < n) {
                if (BF16OUT) {
                    ushort* outb = (ushort*)outv;
                    outb[(size_t)r * 128 + c0] = bf16rn(acc0[i] + bv0);
                    outb[(size_t)r * 128 + c1] = bf16rn(acc1[i] + bv1);
                } else {
                    float* outf = (float*)outv;
                    outf[(size_t)r * 128 + c0] = acc0[i] + bv0;
                    outf[(size_t)r * 128 + c1] = acc1[i] + bv1;
                }
            }
        }
        if (AL) {
#pragma unroll
            for (int i = 0; i < 4; ++i) {
                float ps = acc0[i] * as0 + acc1[i] * as1;
                float pd = acc0[i] * ad0 + acc1[i] * ad1;
                ps += __shfl_xor(ps, 1); ps += __shfl_xor(ps, 2);
                ps += __shfl_xor(ps, 4); ps += __shfl_xor(ps, 8);
                pd += __shfl_xor(pd, 1); pd += __shfl_xor(pd, 2);
                pd += __shfl_xor(pd, 4); pd += __shfl_xor(pd, 8);
                int r = rbase + i;
                if ((lane & 15) == 0 && r < n) {
                    als[r * 4 + ntp] = ps;
                    ald[r * 4 + ntp] = pd;
                }
            }
        }
        __syncthreads();
    }
}

// ----------------- GAT aggregation: one wave per dst node; bf16 feature rows;
// fully-predicated 8-wide gather loop (no serial remainder) -----------------
template <bool CONCAT>
__global__ void agg_kernel(const ushort* __restrict__ hp, const float* __restrict__ als,
                           const float* __restrict__ ald_, const int* __restrict__ rowp,
                           const int* __restrict__ col, const float* __restrict__ bias,
                           float* __restrict__ out, int n) {
    int wid = (blockIdx.x * blockDim.x + threadIdx.x) >> 6;
    if (wid >= n) return;
    int lane = threadIdx.x & 63;
    int d = wid;
    int h = lane >> 4;  // head of this lane's 2 channels
    int c2 = lane * 2;  // channel base 0..126
    int start = rowp[d], end = rowp[d + 1];
    float aldv = ald_[d * 4 + h];
    float eself = __expf(lrelu(als[d * 4 + h] + aldv));
    unsigned sv = *(const unsigned*)(hp + (size_t)d * 128 + c2);
    float a0 = eself * bf16tof((ushort)(sv & 0xffffu));
    float a1 = eself * bf16tof((ushort)(sv >> 16));
    float esum = eself;
    for (int p0 = start; p0 < end; p0 += 8) {
        int sI[8];
#pragma unroll
        for (int j = 0; j < 8; ++j) {
            int p = p0 + j;
            sI[j] = col[p < end ? p : end - 1];
        }
        float q[8];
        unsigned uv[8];
#pragma unroll
        for (int j = 0; j < 8; ++j) {
            q[j] = als[sI[j] * 4 + h];
            uv[j] = *(const unsigned*)(hp + (size_t)sI[j] * 128 + c2);
        }
#pragma unroll
        for (int j = 0; j < 8; ++j) {
            float e = (p0 + j < end) ? __expf(lrelu(q[j] + aldv)) : 0.f;
            a0 += e * bf16tof((ushort)(uv[j] & 0xffffu));
            a1 += e * bf16tof((ushort)(uv[j] >> 16));
            esum += e;
        }
    }
    float inv = 1.f / (esum + 1e-16f);
    a0 *= inv;
    a1 *= inv;
    if (CONCAT) {
        a0 = elu1(a0 + bias[c2]);
        a1 = elu1(a1 + bias[c2 + 1]);
        *(float2*)(out + (size_t)d * 128 + c2) = make_float2(a0, a1);
    } else {
        // mean over heads: combine lanes {l, l^16, l^32, l^48}
        a0 += __shfl_xor(a0, 16); a0 += __shfl_xor(a0, 32);
        a1 += __shfl_xor(a1, 16); a1 += __shfl_xor(a1, 32);
        if (lane < 16) {
            float r0 = elu1(a0 * 0.25f + bias[c2]);
            float r1 = elu1(a1 * 0.25f + bias[c2 + 1]);
            *(float2*)(out + (size_t)d * 32 + c2) = make_float2(r0, r1);
        }
    }
}

// ----------------- mean pool per batch segment (batch sorted) -----------------
__global__ void pool_kernel(const float* __restrict__ h2, const int* __restrict__ batch,
                            int n, float* __restrict__ pooled) {
    int b = blockIdx.x;
    __shared__ int sb[2];
    if (threadIdx.x == 0) {
        int lo = 0, hi = n;
        while (lo < hi) { int mid = (lo + hi) >> 1; if (batch[mid] < b) lo = mid + 1; else hi = mid; }
        sb[0] = lo;
        int lo2 = lo, hi2 = n;
        while (lo2 < hi2) { int mid = (lo2 + hi2) >> 1; if (batch[mid] < b + 1) lo2 = mid + 1; else hi2 = mid; }
        sb[1] = lo2;
    }
    __syncthreads();
    int lo = sb[0], hi = sb[1];
    int c = threadIdx.x & 31, g = threadIdx.x >> 5; // 8 groups of 32
    float acc = 0.f;
    for (int i = lo + g; i < hi; i += 8) acc += h2[(size_t)i * 32 + c];
    __shared__ float red[8][32];
    red[g][c] = acc;
    __syncthreads();
    if (threadIdx.x < 32) {
        float s = 0.f;
#pragma unroll
        for (int g2 = 0; g2 < 8; ++g2) s += red[g2][threadIdx.x];
        float cnt = (float)(hi - lo);
        pooled[b * 32 + threadIdx.x] = s / fmaxf(cnt, 1.f);
    }
}

// ----------------- final_proj + MLP head, one block per batch row -----------------
__global__ void mlp_kernel(const float* __restrict__ pooled, const float* __restrict__ w_fp,
                           const float* __restrict__ b_fp, const float* __restrict__ w_m1,
                           const float* __restrict__ b_m1, const float* __restrict__ w_m2,
                           const float* __restrict__ b_m2, float* __restrict__ out) {
    int b = blockIdx.x, t = threadIdx.x; // 128 threads
    __shared__ float sp[32], so[128];
    if (t < 32) sp[t] = pooled[b * 32 + t];
    __syncthreads();
    float o = b_fp[t];
#pragma unroll 8
    for (int k = 0; k < 32; ++k) o += sp[k] * w_fp[k * 128 + t];
    so[t] = o;
    __syncthreads();
    if (t < 64) {
        float hm = b_m1[t];
        for (int c = 0; c < 128; ++c) hm += so[c] * w_m1[c * 64 + t];
        float v = fmaxf(hm, 0.f) * w_m2[t];
#pragma unroll
        for (int offd = 32; offd > 0; offd >>= 1) v += __shfl_down(v, offd);
        if (t == 0) out[b] = v + b_m2[0];
    }
}

extern "C" void kernel_launch(void* const* d_in, const int* in_sizes, int n_in,
                              void* d_out, int out_size, void* d_ws, size_t ws_size,
                              hipStream_t stream) {
    const float* x = (const float*)d_in[0];
    const int* ei = (const int*)d_in[1];
    const int* batch = (const int*)d_in[2];
    const float* w_in = (const float*)d_in[3];
    const float* b_in = (const float*)d_in[4];
    const float* w[3] = {(const float*)d_in[5], (const float*)d_in[9], (const float*)d_in[13]};
    const float* asrc[3] = {(const float*)d_in[6], (const float*)d_in[10], (const float*)d_in[14]};
    const float* adst[3] = {(const float*)d_in[7], (const float*)d_in[11], (const float*)d_in[15]};
    const float* bb[3] = {(const float*)d_in[8], (const float*)d_in[12], (const float*)d_in[16]};
    const float* w_fp = (const float*)d_in[17];
    const float* b_fp = (const float*)d_in[18];
    const float* w_m1 = (const float*)d_in[19];
    const float* b_m1 = (const float*)d_in[20];
    const float* w_m2 = (const float*)d_in[21];
    const float* b_m2 = (const float*)d_in[22];

    int n = in_sizes[0] / 128;
    int e = in_sizes[1] / 2;
    int B = out_size;

    char* wsb = (char*)d_ws;
    size_t off = 0;
    auto alloc = [&](size_t bytes) -> void* {
        void* p = wsb + off;
        off += (bytes + 255) & ~(size_t)255;
        return p;
    };
    float* hA = (float*)alloc((size_t)n * 128 * 4);
    ushort* hBu = (ushort*)alloc((size_t)n * 128 * 2);
    float* als = (float*)alloc((size_t)n * 4 * 4);
    float* ald = (float*)alloc((size_t)n * 4 * 4);
    int* deg = (int*)alloc((size_t)n * 4);       // reused as cursor
    int* rowp = (int*)alloc((size_t)(n + 1) * 4);
    int* col = (int*)alloc((size_t)e * 4);
    int* bsums = (int*)alloc(4096);
    float* pooled = (float*)alloc((size_t)B * 32 * 4);
    ushort* whi = (ushort*)alloc((size_t)4 * 16384 * 2);
    ushort* wlo = (ushort*)alloc((size_t)4 * 16384 * 2);

    const int* srcp = ei;
    const int* dstp = ei + e;

    // CSR by dst (graph shared by all 3 layers)
    hipMemsetAsync(deg, 0, (size_t)n * 4, stream);
    hist_kernel<<<(e + 255) / 256, 256, 0, stream>>>(dstp, e, deg);
    int nb = (n + 2047) / 2048;
    scan1_kernel<<<nb, 256, 0, stream>>>(deg, n, rowp, bsums);
    scan2_kernel<<<1, 64, 0, stream>>>(bsums, nb);
    scan3_kernel<<<(n + 256) / 256, 256, 0, stream>>>(rowp, bsums, n, e, deg);
    fill_kernel<<<(e + 255) / 256, 256, 0, stream>>>(srcp, dstp, e, deg, col);

    // pre-pack all 4 weight matrices into bf16 hi/lo MFMA fragment order
    wpack_kernel<<<256, 256, 0, stream>>>(w_in, w[0], w[1], w[2], whi, wlo);

    int ntiles = (n + 31) / 32;
    int gblk = ntiles < 1024 ? ntiles : 1024;

    // input projection (bias, fp32 out, no attention logits)
    gemm_mfma_kernel<true, false, false><<<gblk, 512, 0, stream>>>(
        x, whi, wlo, b_in, hA, n, ntiles, nullptr, nullptr, nullptr, nullptr);

    // 3 GAT layers: mfma gemm hA->hBu (bf16, +fused al), aggregate hBu->hA
    for (int L = 0; L < 3; ++L) {
        gemm_mfma_kernel<false, true, true><<<gblk, 512, 0, stream>>>(
            hA, whi + (size_t)(L + 1) * 16384, wlo + (size_t)(L + 1) * 16384, nullptr, hBu, n,
            ntiles, asrc[L], adst[L], als, ald);
        int gridAgg = (n + 3) / 4;
        if (L < 2)
            agg_kernel<true><<<gridAgg, 256, 0, stream>>>(hBu, als, ald, rowp, col, bb[L], hA, n);
        else
            agg_kernel<false><<<gridAgg, 256, 0, stream>>>(hBu, als, ald, rowp, col, bb[L], hA, n);
    }

    // pooling over batch segments, then MLP head
    pool_kernel<<<B, 256, 0, stream>>>(hA, batch, n, pooled);
    mlp_kernel<<<B, 128, 0, stream>>>(pooled, w_fp, b_fp, w_m1, b_m1, w_m2, b_m2, (float*)d_out);
}